// Round 4
// baseline (1563.949 us; speedup 1.0000x reference)
//
#include <hip/hip_runtime.h>

// Grouped SwiGLU MLP, MI355X gfx950.
// Round 5: cross-phase pipelined ds_reads with counted lgkmcnt.
//   Phase P: {opening s_barrier; stage 1 unit; issue 6 ds_reads for phase P+1;
//   s_waitcnt lgkmcnt(6) (waits P's frags, drained under P-1's MFMA);
//   16 MFMA; s_waitcnt vmcnt(8)}. One barrier/phase. LDS drain now overlaps
//   MFMA instead of serializing with it (R3's lgkmcnt(0)-own-reads pattern).
// Derived invariants:
//   - stage unit u(P) per R3 schedule = earliest-legal (1 barrier after the
//     counted-lgkm that retires the last read of the buffer it overwrites).
//   - vmcnt(8) leaves 4 newest units outstanding; every ds_read consumes a
//     unit issued >=5 phases before its covering vmcnt -> resident, no stall.
//   - af double-buffered (af0/af1); bg/bu single-set (WAR by program order).
// Persistent blocks, bid%8 XCD co-location for shared-A L2 reuse.

#define GN 8
#define DN 1024
#define HN 2048
#define ON 1024

typedef __attribute__((ext_vector_type(8))) short short8;
typedef __attribute__((ext_vector_type(4))) float f32x4;
typedef __attribute__((ext_vector_type(4))) unsigned int u32x4;

#define BARR() __builtin_amdgcn_s_barrier()
#define SCHED0() __builtin_amdgcn_sched_barrier(0)
#define LGKM(n)                                                \
  do {                                                         \
    asm volatile("s_waitcnt lgkmcnt(" #n ")" ::: "memory");    \
    __builtin_amdgcn_sched_barrier(0);                         \
  } while (0)
#define VM8() asm volatile("s_waitcnt vmcnt(8)" ::: "memory")

// ds_read_b128 with compile-time byte offset; opaque to alias analysis.
#define DS128(dst, base, imm)                                                  \
  asm volatile("ds_read_b128 %0, %1 offset:" #imm                              \
               : "=v"(dst)                                                     \
               : "v"((const __attribute__((address_space(3))) unsigned short*)(base)))

__device__ __forceinline__ void async16(const void* g, void* l) {
  __builtin_amdgcn_global_load_lds(
      (const __attribute__((address_space(1))) void*)g,
      (__attribute__((address_space(3))) void*)l, 16, 0, 0);
}

__device__ __forceinline__ unsigned short f2bf(float f) {
  unsigned int u = __float_as_uint(f);
  u += 0x7FFFu + ((u >> 16) & 1u);  // round-to-nearest-even
  return (unsigned short)(u >> 16);
}

__global__ __launch_bounds__(256) void cvt_f32_bf16(
    const float* __restrict__ in, unsigned short* __restrict__ out, int n) {
  int t = blockIdx.x * 256 + threadIdx.x;
  int i = t * 8;
  if (i >= n) return;
  f32x4 a = *(const f32x4*)(in + i);
  f32x4 b = *(const f32x4*)(in + i + 4);
  u32x4 r;
  r.x = (unsigned)f2bf(a.x) | ((unsigned)f2bf(a.y) << 16);
  r.y = (unsigned)f2bf(a.z) | ((unsigned)f2bf(a.w) << 16);
  r.z = (unsigned)f2bf(b.x) | ((unsigned)f2bf(b.y) << 16);
  r.w = (unsigned)f2bf(b.z) | ((unsigned)f2bf(b.w) << 16);
  *(u32x4*)(out + i) = r;
}

// ---------------- Phase 1: gate/up dual GEMM + SwiGLU -> hidden bf16 --------
// 256 blocks: bid = n(4b)*16 + g(3b)*2 + mh(1b). bid%8 groups same-(g,mh)
// blocks (shared A panel) on one XCD. 16 m-tiles/block, TOTK=256 K-tiles.
__global__ __launch_bounds__(512, 2) void gemm1_swiglu(
    const unsigned short* __restrict__ Xb, const unsigned short* __restrict__ Wgb,
    const unsigned short* __restrict__ Wub, unsigned short* __restrict__ Hid) {
  extern __shared__ unsigned short sm[];
  unsigned short* sA = sm;            // 4 bufs x 256x32 (64KB)
  unsigned short* sG = sm + 32768;    // 4 bufs x 128x32 (32KB)
  unsigned short* sU = sm + 49152;    // 4 bufs x 128x32 (32KB)

  const int bid = blockIdx.x;
  const int g = (bid & 15) >> 1;
  const int mh = bid & 1;
  const int n0 = (bid >> 4) * 128;

  const int tid = threadIdx.x;
  const int lane = tid & 63;
  const int w = tid >> 6;
  const int wm = w >> 2, wn = w & 3;
  const int fr = lane & 15, fc = lane >> 4;
  const int sR = (fc + ((fr >> 1) & 3)) & 3;  // read-side chunk swizzle

  const unsigned short* aBase[2];
  unsigned short* aDst[2];
#pragma unroll
  for (int j = 0; j < 2; ++j) {
    int R = j * 128 + w * 16 + (lane >> 2);
    int c = ((lane & 3) - ((R >> 1) & 3)) & 3;
    aBase[j] = Xb + ((size_t)((mh * 4096 + R) * 8 + g)) * DN + c * 8;
    aDst[j] = &sA[(j * 128 + w * 16) * 32];
  }
  const unsigned short *gSrc, *uSrc;
  unsigned short *gDst, *uDst;
  {
    int R = w * 16 + (lane >> 2);
    int c = ((lane & 3) - ((R >> 1) & 3)) & 3;
    gSrc = Wgb + ((size_t)(g * HN + n0 + R)) * DN + c * 8;
    uSrc = Wub + ((size_t)(g * HN + n0 + R)) * DN + c * 8;
    gDst = &sG[(w * 16) * 32];
    uDst = &sU[(w * 16) * 32];
  }

  auto stageA = [&](int t, int kk) {  // 2 loads/thread, guarded
    if (t >= 256) return;
    const int buf = (t & 1) * 2 + kk;
    const size_t off = (size_t)(t >> 4) * (256u * 8u * DN) + (t & 15) * 64 + kk * 32;
#pragma unroll
    for (int j = 0; j < 2; ++j) async16(aBase[j] + off, aDst[j] + buf * 8192);
  };
  auto stageB = [&](int t, int kk) {  // 2 loads/thread (Bg + Bu), guarded
    if (t >= 256) return;
    const int buf = (t & 1) * 2 + kk;
    const int ko = (t & 15) * 64 + kk * 32;
    async16(gSrc + ko, gDst + buf * 4096);
    async16(uSrc + ko, uDst + buf * 4096);
  };
  auto aPtr = [&](int t, int kk) {
    return sA + ((t & 1) * 2 + kk) * 8192 + (wm * 128 + fr) * 32 + sR * 8;
  };
  auto readAlo = [&](int t, int kk, short8* a) {
    const unsigned short* p = aPtr(t, kk);
    DS128(a[0], p, 0);
    DS128(a[1], p, 1024);
    DS128(a[2], p, 2048);
    DS128(a[3], p, 3072);
  };
  auto readAhi = [&](int t, int kk, short8* a) {
    const unsigned short* p = aPtr(t, kk);
    DS128(a[4], p, 4096);
    DS128(a[5], p, 5120);
    DS128(a[6], p, 6144);
    DS128(a[7], p, 7168);
  };
  auto readB = [&](const unsigned short* base, int t, int kk, short8* b) {
    const unsigned short* p =
        base + ((t & 1) * 2 + kk) * 4096 + (wn * 32 + fr) * 32 + sR * 8;
    DS128(b[0], p, 0);
    DS128(b[1], p, 1024);
  };

  f32x4 accg[8][2], accu[8][2];
#pragma unroll
  for (int mi = 0; mi < 8; ++mi)
#pragma unroll
    for (int ni = 0; ni < 2; ++ni) {
      accg[mi][ni] = (f32x4)(0.0f);
      accu[mi][ni] = (f32x4)(0.0f);
    }

  auto mm16 = [&](const short8* a, const short8* b, f32x4(*acc)[2]) {
    __builtin_amdgcn_s_setprio(1);
#pragma unroll
    for (int mi = 0; mi < 8; ++mi)
#pragma unroll
      for (int ni = 0; ni < 2; ++ni)
        acc[mi][ni] = __builtin_amdgcn_mfma_f32_16x16x32_bf16(
            a[mi], b[ni], acc[mi][ni], 0, 0, 0);
    __builtin_amdgcn_s_setprio(0);
  };

  // prologue: 7 units; vmcnt(10) => A(0,0),B(0,0) resident; pre-read frags(p0)
  stageA(0, 0); stageB(0, 0); stageA(0, 1); stageB(0, 1);
  stageA(1, 0); stageB(1, 0); stageA(1, 1);
  asm volatile("s_waitcnt vmcnt(10)" ::: "memory");
  BARR();
  short8 af0[8], af1[8], bg[2], bu[2];
  readAlo(0, 0, af0); readAhi(0, 0, af0); readB(sG, 0, 0, bg);

  const int q = lane >> 4, cl = lane & 15;
  const int NIT = 128;  // 256 K-tiles / 2
#pragma unroll 1
  for (int it = 0; it < NIT; ++it) {
    const int T = 2 * it;
    // ---- p0: MFMA gate(T,k0) ----
    BARR(); SCHED0();
    stageB(T + 1, 1);
    readB(sU, T, 0, bu); readAlo(T, 1, af1);
    LGKM(6);
    mm16(af0, bg, accg);
    VM8();
    // ---- p1: MFMA up(T,k0) ----
    BARR(); SCHED0();
    stageA(T + 2, 0);
    readAhi(T, 1, af1); readB(sG, T, 1, bg);
    LGKM(6);
    mm16(af0, bu, accu);
    VM8();
    // ---- p2: MFMA gate(T,k1) ----
    BARR(); SCHED0();
    stageB(T + 2, 0);
    readB(sU, T, 1, bu); readAlo(T + 1, 0, af0);
    LGKM(6);
    mm16(af1, bg, accg);
    VM8();
    // ---- p3: MFMA up(T,k1) ----
    BARR(); SCHED0();
    stageA(T + 2, 1);
    readAhi(T + 1, 0, af0); readB(sG, T + 1, 0, bg);
    LGKM(6);
    mm16(af1, bu, accu);
    VM8();
    // ---- p4: MFMA gate(T+1,k0) ----
    BARR(); SCHED0();
    stageB(T + 2, 1);
    readB(sU, T + 1, 0, bu); readAlo(T + 1, 1, af1);
    LGKM(6);
    mm16(af0, bg, accg);
    VM8();
    // ---- p5: MFMA up(T+1,k0) ----
    BARR(); SCHED0();
    stageA(T + 3, 0);
    readAhi(T + 1, 1, af1); readB(sG, T + 1, 1, bg);
    LGKM(6);
    mm16(af0, bu, accu);
    VM8();
    // ---- p6: MFMA gate(T+1,k1) ----
    BARR(); SCHED0();
    stageB(T + 3, 0);
    readB(sU, T + 1, 1, bu); readAlo(T + 2, 0, af0);
    LGKM(6);
    mm16(af1, bg, accg);
    VM8();
    // ---- p7: MFMA up(T+1,k1) ----
    BARR(); SCHED0();
    stageA(T + 3, 1);
    readAhi(T + 2, 0, af0); readB(sG, T + 2, 0, bg);
    LGKM(6);
    mm16(af1, bu, accu);
    VM8();
    // ---- m-tile epilogue (every 8 iterations) ----
    if ((T & 15) == 14) {
      const int m0 = (mh * 16 + (T >> 4)) * 256;
#pragma unroll
      for (int mi = 0; mi < 8; ++mi)
#pragma unroll
        for (int ni = 0; ni < 2; ++ni) {
          int hcol = n0 + wn * 32 + ni * 16 + cl;
#pragma unroll
          for (int i2 = 0; i2 < 4; ++i2) {
            int b = m0 + wm * 128 + mi * 16 + q * 4 + i2;
            float gf = accg[mi][ni][i2];
            float uf = accu[mi][ni][i2];
            float hv = (gf / (1.0f + __expf(-gf))) * uf;
            Hid[((size_t)(b * 8 + g)) * HN + hcol] = f2bf(hv);
          }
          accg[mi][ni] = (f32x4)(0.0f);
          accu[mi][ni] = (f32x4)(0.0f);
        }
    }
  }
}

// ---------------- Phase 2: hidden @ Wd^T -> out fp32 ------------------------
// 256 blocks: bid = n(2b)*64 + g(3b)*8 + mq(3b). bid%8 = mq groups shared-A
// blocks per XCD. 4 m-tiles/block, TOTK=128 K-tiles.
__global__ __launch_bounds__(512, 2) void gemm2_down(
    const unsigned short* __restrict__ Hid, const unsigned short* __restrict__ Wdb,
    float* __restrict__ Out) {
  extern __shared__ unsigned short sm[];
  unsigned short* sA = sm;            // 4 x 256x32
  unsigned short* sB = sm + 32768;    // 4 x 256x32

  const int bid = blockIdx.x;
  const int g = (bid & 63) >> 3;
  const int mq = bid & 7;
  const int n0 = (bid >> 6) * 256;

  const int tid = threadIdx.x;
  const int lane = tid & 63;
  const int w = tid >> 6;
  const int wm = w >> 2, wn = w & 3;
  const int fr = lane & 15, fc = lane >> 4;
  const int sR = (fc + ((fr >> 1) & 3)) & 3;

  const unsigned short* aBase[2];
  const unsigned short* bSrc[2];
  unsigned short* aDst[2];
  unsigned short* bDst[2];
#pragma unroll
  for (int j = 0; j < 2; ++j) {
    int R = j * 128 + w * 16 + (lane >> 2);
    int c = ((lane & 3) - ((R >> 1) & 3)) & 3;
    aBase[j] = Hid + ((size_t)((mq * 1024 + R) * 8 + g)) * HN + c * 8;
    bSrc[j] = Wdb + ((size_t)(g * ON + n0 + R)) * HN + c * 8;
    aDst[j] = &sA[(j * 128 + w * 16) * 32];
    bDst[j] = &sB[(j * 128 + w * 16) * 32];
  }

  auto stageA = [&](int t, int kk) {
    if (t >= 128) return;
    const int buf = (t & 1) * 2 + kk;
    const size_t off = (size_t)(t >> 5) * (256u * 8u * HN) + (t & 31) * 64 + kk * 32;
#pragma unroll
    for (int j = 0; j < 2; ++j) async16(aBase[j] + off, aDst[j] + buf * 8192);
  };
  auto stageB = [&](int t, int kk) {
    if (t >= 128) return;
    const int buf = (t & 1) * 2 + kk;
    const int ko = (t & 31) * 64 + kk * 32;
#pragma unroll
    for (int j = 0; j < 2; ++j) async16(bSrc[j] + ko, bDst[j] + buf * 8192);
  };
  auto aPtr = [&](int t, int kk) {
    return sA + ((t & 1) * 2 + kk) * 8192 + (wm * 128 + fr) * 32 + sR * 8;
  };
  auto readAlo = [&](int t, int kk, short8* a) {
    const unsigned short* p = aPtr(t, kk);
    DS128(a[0], p, 0);
    DS128(a[1], p, 1024);
    DS128(a[2], p, 2048);
    DS128(a[3], p, 3072);
  };
  auto readAhi = [&](int t, int kk, short8* a) {
    const unsigned short* p = aPtr(t, kk);
    DS128(a[4], p, 4096);
    DS128(a[5], p, 5120);
    DS128(a[6], p, 6144);
    DS128(a[7], p, 7168);
  };
  auto readB = [&](int t, int kk, int nb, short8* b) {
    const unsigned short* p =
        sB + ((t & 1) * 2 + kk) * 8192 + (wn * 64 + nb * 16 + fr) * 32 + sR * 8;
    DS128(b[0], p, 0);
    DS128(b[1], p, 1024);
  };

  f32x4 acc[8][4];
#pragma unroll
  for (int mi = 0; mi < 8; ++mi)
#pragma unroll
    for (int ni = 0; ni < 4; ++ni) acc[mi][ni] = (f32x4)(0.0f);

  auto mm16 = [&](const short8* a, const short8* b, int nb) {
    __builtin_amdgcn_s_setprio(1);
#pragma unroll
    for (int mi = 0; mi < 8; ++mi)
#pragma unroll
      for (int nj = 0; nj < 2; ++nj)
        acc[mi][nb + nj] = __builtin_amdgcn_mfma_f32_16x16x32_bf16(
            a[mi], b[nj], acc[mi][nb + nj], 0, 0, 0);
    __builtin_amdgcn_s_setprio(0);
  };

  stageA(0, 0); stageB(0, 0); stageA(0, 1); stageB(0, 1);
  stageA(1, 0); stageB(1, 0); stageA(1, 1);
  asm volatile("s_waitcnt vmcnt(10)" ::: "memory");
  BARR();
  short8 af0[8], af1[8], b01[2], b23[2];
  readAlo(0, 0, af0); readAhi(0, 0, af0); readB(0, 0, 0, b01);

  const int q = lane >> 4, cl = lane & 15;
  const int NIT = 64;  // 128 K-tiles / 2
#pragma unroll 1
  for (int it = 0; it < NIT; ++it) {
    const int T = 2 * it;
    // ---- p0 ----
    BARR(); SCHED0();
    stageB(T + 1, 1);
    readB(T, 0, 2, b23); readAlo(T, 1, af1);
    LGKM(6);
    mm16(af0, b01, 0);
    VM8();
    // ---- p1 ----
    BARR(); SCHED0();
    stageA(T + 2, 0);
    readAhi(T, 1, af1); readB(T, 1, 0, b01);
    LGKM(6);
    mm16(af0, b23, 2);
    VM8();
    // ---- p2 ----
    BARR(); SCHED0();
    stageB(T + 2, 0);
    readB(T, 1, 2, b23); readAlo(T + 1, 0, af0);
    LGKM(6);
    mm16(af1, b01, 0);
    VM8();
    // ---- p3 ----
    BARR(); SCHED0();
    stageA(T + 2, 1);
    readAhi(T + 1, 0, af0); readB(T + 1, 0, 0, b01);
    LGKM(6);
    mm16(af1, b23, 2);
    VM8();
    // ---- p4 ----
    BARR(); SCHED0();
    stageB(T + 2, 1);
    readB(T + 1, 0, 2, b23); readAlo(T + 1, 1, af1);
    LGKM(6);
    mm16(af0, b01, 0);
    VM8();
    // ---- p5 ----
    BARR(); SCHED0();
    stageA(T + 3, 0);
    readAhi(T + 1, 1, af1); readB(T + 1, 1, 0, b01);
    LGKM(6);
    mm16(af0, b23, 2);
    VM8();
    // ---- p6 ----
    BARR(); SCHED0();
    stageB(T + 3, 0);
    readB(T + 1, 1, 2, b23); readAlo(T + 2, 0, af0);
    LGKM(6);
    mm16(af1, b01, 0);
    VM8();
    // ---- p7 ----
    BARR(); SCHED0();
    stageA(T + 3, 1);
    readAhi(T + 2, 0, af0); readB(T + 2, 0, 0, b01);
    LGKM(6);
    mm16(af1, b23, 2);
    VM8();
    // ---- m-tile epilogue (every 16 iterations) ----
    if ((T & 31) == 30) {
      const int m0 = (mq * 4 + (T >> 5)) * 256;
#pragma unroll
      for (int mi = 0; mi < 8; ++mi)
#pragma unroll
        for (int ni = 0; ni < 4; ++ni) {
          int o = n0 + wn * 64 + ni * 16 + cl;
#pragma unroll
          for (int i2 = 0; i2 < 4; ++i2) {
            int b = m0 + wm * 128 + mi * 16 + q * 4 + i2;
            Out[((size_t)(b * 8 + g)) * ON + o] = acc[mi][ni][i2];
          }
          acc[mi][ni] = (f32x4)(0.0f);
        }
    }
  }
}

extern "C" void kernel_launch(void* const* d_in, const int* in_sizes, int n_in,
                              void* d_out, int out_size, void* d_ws, size_t ws_size,
                              hipStream_t stream) {
  const float* x  = (const float*)d_in[0];   // [65536, 1024]
  const float* Wg = (const float*)d_in[1];   // [8, 2048, 1024]
  const float* Wu = (const float*)d_in[2];   // [8, 2048, 1024]
  const float* Wd = (const float*)d_in[3];   // [8, 1024, 2048]
  float* out = (float*)d_out;                // [65536, 1024]

  const int NX = 65536 * 1024;
  const int NW = GN * HN * DN;

  unsigned short* xb = (unsigned short*)d_ws;
  unsigned short* wg = xb + (size_t)NX;
  unsigned short* wu = wg + (size_t)NW;
  unsigned short* wd = wu + (size_t)NW;
  unsigned short* hid = wd + (size_t)NW;     // [65536, 2048] bf16

  static bool once = false;
  if (!once) {
    hipFuncSetAttribute((const void*)gemm1_swiglu,
                        hipFuncAttributeMaxDynamicSharedMemorySize, 131072);
    hipFuncSetAttribute((const void*)gemm2_down,
                        hipFuncAttributeMaxDynamicSharedMemorySize, 131072);
    once = true;
  }

  cvt_f32_bf16<<<NX / 8 / 256, 256, 0, stream>>>(x, xb, NX);
  cvt_f32_bf16<<<NW / 8 / 256, 256, 0, stream>>>(Wg, wg, NW);
  cvt_f32_bf16<<<NW / 8 / 256, 256, 0, stream>>>(Wu, wu, NW);
  cvt_f32_bf16<<<NW / 8 / 256, 256, 0, stream>>>(Wd, wd, NW);

  gemm1_swiglu<<<dim3(256), dim3(512), 131072, stream>>>(xb, wg, wu, hid);
  gemm2_down<<<dim3(256), dim3(512), 131072, stream>>>(hid, wd, out);
}